// Round 6
// baseline (3091.120 us; speedup 1.0000x reference)
//
#include <hip/hip_runtime.h>
#include <hip/hip_bf16.h>

#define B_ 256
#define T_ 512
#define E_ 128
#define H_ 256

typedef __attribute__((ext_vector_type(8))) short short8;
typedef __attribute__((ext_vector_type(4))) float f32x4;
typedef unsigned short u16;

#define MFMA_BF16(a, b, c) __builtin_amdgcn_mfma_f32_16x16x32_bf16((a), (b), (c), 0, 0, 0)

__device__ __forceinline__ u16 f2bf(float f) {
    union { float f; unsigned int u; } v; v.f = f;
    unsigned int u = v.u;
    unsigned int r = (u + 0x7fffu + ((u >> 16) & 1u)) >> 16;  // RNE
    return (u16)r;
}
__device__ __forceinline__ float bflo(unsigned int u) {
    union { unsigned int u; float f; } v; v.u = u << 16; return v.f;
}
__device__ __forceinline__ float bfhi(unsigned int u) {
    union { unsigned int u; float f; } v; v.u = u & 0xffff0000u; return v.f;
}
__device__ __forceinline__ f32x4 up2(uint2 p) {
    f32x4 r; r[0] = bflo(p.x); r[1] = bfhi(p.x); r[2] = bflo(p.y); r[3] = bfhi(p.y); return r;
}
__device__ __forceinline__ uint2 pk4(float a, float b, float c, float d) {
    uint2 o;
    o.x = (unsigned)f2bf(a) | ((unsigned)f2bf(b) << 16);
    o.y = (unsigned)f2bf(c) | ((unsigned)f2bf(d) << 16);
    return o;
}
__device__ __forceinline__ float sigm(float x) { return 1.f / (1.f + __expf(-x)); }

// ---------------- fp32 -> bf16 weight conversion ----------------
__global__ void f32_to_bf16_kernel(const float* __restrict__ src, u16* __restrict__ dst, int n2) {
    int i = blockIdx.x * blockDim.x + threadIdx.x;
    if (i < n2) {
        float2 v = ((const float2*)src)[i];
        ushort2 o; o.x = f2bf(v.x); o.y = f2bf(v.y);
        ((ushort2*)dst)[i] = o;
    }
}

// ---------------- xp chunk GEMM (R3-proven layout) ----------------
// xp (uint2 per lane): slot = dir*C + lt, then [slot][btile16][gtile48][lane64];
// lane(quad,nl) packs rr=0..3: value = xp(unit gt*16+quad*4+rr, batch btile*16+nl).
// gates r,z (gt<32) carry b_ih+b_hh; n-gate carries b_ih only.
#define XP_SLOT_U2 49152   // 16*48*64 uint2 per t-slot
#define XP_SLOT_B  393216

__launch_bounds__(512, 1)
__global__ void xp_gemm_kernel(const int* __restrict__ x, const float* __restrict__ emb,
                               const u16* __restrict__ wih,
                               const float* __restrict__ bih_f, const float* __restrict__ bhh_f,
                               const float* __restrict__ bih_b, const float* __restrict__ bhh_b,
                               u16* __restrict__ xp, int C, int c0) {
    const int per_dir = C * 4;
    const int dir = (blockIdx.x >= per_dir) ? 1 : 0;
    const int mb  = blockIdx.x - dir * per_dir;
    const int lt  = mb >> 2;
    const int b0  = (mb & 3) << 6;          // 64 batch rows per block
    const int t   = dir ? (T_ - 1 - (c0 + lt)) : (c0 + lt);
    const int tid  = threadIdx.x;
    const int wv   = tid >> 6;
    const int lane = tid & 63;
    const int nl   = lane & 15;
    const int quad = lane >> 4;

    __shared__ u16 A[64][136];

    const u16*   wih_d = wih + (size_t)dir * (768 * 128);
    const float* bih   = dir ? bih_b : bih_f;
    const float* bhh   = dir ? bhh_b : bhh_f;

    short8 wfrag[6][4];
#pragma unroll
    for (int j = 0; j < 6; j++) {
        int gt = wv * 6 + j;
        const u16* p = wih_d + (size_t)(gt * 16 + nl) * 128 + quad * 8;
#pragma unroll
        for (int kt = 0; kt < 4; kt++) wfrag[j][kt] = *(const short8*)(p + kt * 32);
    }

#pragma unroll
    for (int i = 0; i < 4; i++) {
        int idx = tid + i * 512;
        int r = idx >> 5, c = idx & 31;
        int tok = x[(b0 + r) * T_ + t];
        float4 v = *(const float4*)(emb + (size_t)tok * E_ + c * 4);
        *(uint2*)&A[r][c * 4] = pk4(v.x, v.y, v.z, v.w);
    }
    __syncthreads();

    f32x4 acc[6][4];
#pragma unroll
    for (int j = 0; j < 6; j++)
#pragma unroll
        for (int mi = 0; mi < 4; mi++) acc[j][mi] = (f32x4){0, 0, 0, 0};

#pragma unroll
    for (int kt = 0; kt < 4; kt++) {
        short8 a[4];
#pragma unroll
        for (int mi = 0; mi < 4; mi++)
            a[mi] = *(const short8*)&A[mi * 16 + nl][quad * 8 + kt * 32];
#pragma unroll
        for (int j = 0; j < 6; j++)
#pragma unroll
            for (int mi = 0; mi < 4; mi++)
                acc[j][mi] = MFMA_BF16(wfrag[j][kt], a[mi], acc[j][mi]);  // w=A, emb=B
    }

    const int slot = dir * C + lt;
#pragma unroll
    for (int j = 0; j < 6; j++) {
        int gt = wv * 6 + j;
        int gate = gt >> 4;
        const float4 bi = *(const float4*)(bih + gt * 16 + quad * 4);
        const float4 bh = *(const float4*)(bhh + gt * 16 + quad * 4);
        float bb[4];
        bb[0] = bi.x + (gate < 2 ? bh.x : 0.f);
        bb[1] = bi.y + (gate < 2 ? bh.y : 0.f);
        bb[2] = bi.z + (gate < 2 ? bh.z : 0.f);
        bb[3] = bi.w + (gate < 2 ? bh.w : 0.f);
#pragma unroll
        for (int mi = 0; mi < 4; mi++) {
            int btile = ((mb & 3) << 2) + mi;
            f32x4 v = acc[j][mi];
            size_t base = (((size_t)slot * 16 + btile) * 48 + gt) * 64 + lane;
            ((uint2*)xp)[base] = pk4(v[0] + bb[0], v[1] + bb[1], v[2] + bb[2], v[3] + bb[3]);
        }
    }
}

// ---------------- GRU chunk recurrence ----------------
// 32 blocks (dir x 16 btiles), 512 thr = 8 waves, 1 block/CU (144 KB LDS).
// Wave wv owns units [wv*32, wv*32+32); lane(quad,nl): batch b_base+nl,
// units wv*32+16*hh+quad*4+rr.
// Weight residency: 4 sets (r,h0)(r,h1)(z,h0)(z,h1) PINNED to AGPRs via
// empty inline-asm "+a" constraints inside the loop (gfx950 MFMA reads
// A-operands from AGPRs directly — no copies, no per-step refetch).
// (n,h0),(n,h1) sets in LDS, fragment-linear (conflict-free b128 reads).
__launch_bounds__(512, 1)
__global__ void gru_chunk_kernel(const u16* __restrict__ xp, const u16* __restrict__ whh,
                                 const float* __restrict__ bhh_f, const float* __restrict__ bhh_b,
                                 const int* __restrict__ lengths,
                                 float* __restrict__ hstate,   // [dir][256][256] f32
                                 int C, int c0) {
    const int dir    = blockIdx.x >> 4;
    const int btile  = blockIdx.x & 15;
    const int b_base = btile << 4;
    const int wv     = threadIdx.x >> 6;
    const int lane   = threadIdx.x & 63;
    const int nl     = lane & 15;
    const int quad   = lane >> 4;

    __shared__ u16 hfr[2][4096];     // 2 x 8KB h mirrors, fragment-linear
    __shared__ u16 wn[2][32768];     // 128KB: (n,h0),(n,h1) sets, fragment-linear

    const u16*   whh_d = whh + (size_t)dir * (768 * 256);
    const float* bhh   = dir ? bhh_b : bhh_f;

    // stage wn[sidx]: entry (wv_e,kt_e,ln_e) <- whh row 512+wv_e*32+sidx*16+(ln_e&15),
    // cols (ln_e>>4)*8 + kt_e*32
    for (int e = threadIdx.x; e < 8192; e += 512) {
        int sidx = e >> 12, e2 = e & 4095;
        int wv_e = e2 >> 9, kt_e = (e2 >> 6) & 7, ln_e = e2 & 63;
        const u16* src = whh_d + (size_t)(512 + wv_e * 32 + sidx * 16 + (ln_e & 15)) * 256
                       + (ln_e >> 4) * 8 + kt_e * 32;
        *(short8*)&wn[sidx][e2 * 8] = *(const short8*)src;
    }

    // AGPR-pinned w_hh sets: (r,h0)(r,h1)(z,h0)(z,h1)
    short8 w[4][8];
    {
        const int row[4] = {wv * 32 + nl, wv * 32 + 16 + nl,
                            256 + wv * 32 + nl, 256 + wv * 32 + 16 + nl};
#pragma unroll
        for (int gh = 0; gh < 4; gh++) {
            const u16* p = whh_d + (size_t)row[gh] * 256 + quad * 8;
#pragma unroll
            for (int kt = 0; kt < 8; kt++) w[gh][kt] = *(const short8*)(p + kt * 32);
        }
    }

    const float4 bnh0 = *(const float4*)(bhh + 512 + wv * 32 + quad * 4);
    const float4 bnh1 = *(const float4*)(bhh + 512 + wv * 32 + 16 + quad * 4);
    const int len = lengths[b_base + nl];

    // h master copy (fp32) + initial mirror write
    float hreg[2][4];
    const int o0 = quad * 4, o1 = 16 + quad * 4;
    const int widx0 = (wv * 64 + (o0 >> 3) * 16 + nl) * 8 + (o0 & 7);
    const int widx1 = (wv * 64 + (o1 >> 3) * 16 + nl) * 8 + (o1 & 7);
    if (c0 == 0) {
#pragma unroll
        for (int hh = 0; hh < 2; hh++)
#pragma unroll
            for (int rr = 0; rr < 4; rr++) hreg[hh][rr] = 0.f;
    } else {
        const float* hs = hstate + ((size_t)(dir * 256 + b_base + nl)) * 256 + wv * 32;
        float4 h0 = *(const float4*)(hs + o0);
        float4 h1 = *(const float4*)(hs + o1);
        hreg[0][0] = h0.x; hreg[0][1] = h0.y; hreg[0][2] = h0.z; hreg[0][3] = h0.w;
        hreg[1][0] = h1.x; hreg[1][1] = h1.y; hreg[1][2] = h1.z; hreg[1][3] = h1.w;
    }
    *(uint2*)&hfr[0][widx0] = pk4(hreg[0][0], hreg[0][1], hreg[0][2], hreg[0][3]);
    *(uint2*)&hfr[0][widx1] = pk4(hreg[1][0], hreg[1][1], hreg[1][2], hreg[1][3]);

    // xp pointers (R3-proven): gate g tile for this wave = g*16 + wv*2 (+hh)
    const uint2* pg0;
    const uint2* pg1;
    const uint2* pg2;
    {
        size_t base = (((size_t)(dir * C) * 16 + btile) * 48) * 64 + lane;
        pg0 = (const uint2*)xp + base + (0 * 16 + wv * 2) * 64;
        pg1 = (const uint2*)xp + base + (1 * 16 + wv * 2) * 64;
        pg2 = (const uint2*)xp + base + (2 * 16 + wv * 2) * 64;
    }
    uint2 pf0[2], pf1[2], pf2[2];
    pf0[0] = pg0[0]; pf0[1] = pg0[64];
    pf1[0] = pg1[0]; pf1[1] = pg1[64];
    pf2[0] = pg2[0]; pf2[1] = pg2[64];

    __syncthreads();

    for (int ls = 0; ls < C; ls++) {
        const int s = c0 + ls;
        const int t = dir ? (T_ - 1 - s) : s;
        const int cur = ls & 1, nxt = cur ^ 1;

        // Pin the 4 weight sets to AGPRs, live at every iteration. Empty asm:
        // zero instructions, forces register class + liveness (no remat/refetch).
        asm volatile("" : "+a"(w[0][0]), "+a"(w[0][1]), "+a"(w[0][2]), "+a"(w[0][3]),
                          "+a"(w[0][4]), "+a"(w[0][5]), "+a"(w[0][6]), "+a"(w[0][7]),
                          "+a"(w[1][0]), "+a"(w[1][1]), "+a"(w[1][2]), "+a"(w[1][3]),
                          "+a"(w[1][4]), "+a"(w[1][5]), "+a"(w[1][6]), "+a"(w[1][7]));
        asm volatile("" : "+a"(w[2][0]), "+a"(w[2][1]), "+a"(w[2][2]), "+a"(w[2][3]),
                          "+a"(w[2][4]), "+a"(w[2][5]), "+a"(w[2][6]), "+a"(w[2][7]),
                          "+a"(w[3][0]), "+a"(w[3][1]), "+a"(w[3][2]), "+a"(w[3][3]),
                          "+a"(w[3][4]), "+a"(w[3][5]), "+a"(w[3][6]), "+a"(w[3][7]));

        // consume prefetched xp
        f32x4 accr[2], accz[2], accn[2], xpn[2];
        accr[0] = up2(pf0[0]); accr[1] = up2(pf0[1]);
        accz[0] = up2(pf1[0]); accz[1] = up2(pf1[1]);
        xpn[0]  = up2(pf2[0]); xpn[1]  = up2(pf2[1]);
        accn[0] = (f32x4){bnh0.x, bnh0.y, bnh0.z, bnh0.w};
        accn[1] = (f32x4){bnh1.x, bnh1.y, bnh1.z, bnh1.w};

        // prefetch next step (last iter reads the pad/next-dir slot — valid, unused)
        pg0 += XP_SLOT_U2; pg1 += XP_SLOT_U2; pg2 += XP_SLOT_U2;
        pf0[0] = pg0[0]; pf0[1] = pg0[64];
        pf1[0] = pg1[0]; pf1[1] = pg1[64];
        pf2[0] = pg2[0]; pf2[1] = pg2[64];

#pragma unroll
        for (int kt = 0; kt < 8; kt++) {
            short8 hv = *(const short8*)&hfr[cur][(kt * 64 + lane) * 8];
            accr[0] = MFMA_BF16(w[0][kt], hv, accr[0]);
            accr[1] = MFMA_BF16(w[1][kt], hv, accr[1]);
            accz[0] = MFMA_BF16(w[2][kt], hv, accz[0]);
            accz[1] = MFMA_BF16(w[3][kt], hv, accz[1]);
            short8 bn0 = *(const short8*)&wn[0][((wv * 8 + kt) * 64 + lane) * 8];
            accn[0] = MFMA_BF16(bn0, hv, accn[0]);
            short8 bn1 = *(const short8*)&wn[1][((wv * 8 + kt) * 64 + lane) * 8];
            accn[1] = MFMA_BF16(bn1, hv, accn[1]);
        }

        const bool upd = (t < len);
#pragma unroll
        for (int hh = 0; hh < 2; hh++) {
#pragma unroll
            for (int rr = 0; rr < 4; rr++) {
                float r = sigm(accr[hh][rr]);
                float z = sigm(accz[hh][rr]);
                float npre = xpn[hh][rr] + r * accn[hh][rr];
                float nn = 1.f - 2.f / (1.f + __expf(2.f * npre));
                float hn = nn + z * (hreg[hh][rr] - nn);
                if (upd) hreg[hh][rr] = hn;
            }
        }
        *(uint2*)&hfr[nxt][widx0] = pk4(hreg[0][0], hreg[0][1], hreg[0][2], hreg[0][3]);
        *(uint2*)&hfr[nxt][widx1] = pk4(hreg[1][0], hreg[1][1], hreg[1][2], hreg[1][3]);
        __syncthreads();
    }

    // carry h out (coalesced float4)
    float* hs = hstate + ((size_t)(dir * 256 + b_base + nl)) * 256 + wv * 32;
    *(float4*)(hs + o0) = (float4){hreg[0][0], hreg[0][1], hreg[0][2], hreg[0][3]};
    *(float4*)(hs + o1) = (float4){hreg[1][0], hreg[1][1], hreg[1][2], hreg[1][3]};
}

// ---------------- FC head + row L2-normalize ----------------
__global__ void fc_head_kernel(const float* __restrict__ hstate,
                               const float* __restrict__ fc1w, const float* __restrict__ fc1b,
                               const float* __restrict__ fc2w, const float* __restrict__ fc2b,
                               float* __restrict__ out) {
    int row = blockIdx.x;
    int tid = threadIdx.x;  // 128
    __shared__ float hrow[512];
    __shared__ float hid[128];

    {
        int dir = tid >> 6, u = (tid & 63) * 4;
        float4 hv = *(const float4*)(hstate + ((size_t)(dir * 256 + row)) * 256 + u);
        *(float4*)(hrow + tid * 4) = hv;
    }
    __syncthreads();

    float acc = fc1b[tid];
    const float* wrow = fc1w + (size_t)tid * 512;
#pragma unroll 4
    for (int k = 0; k < 512; k += 4) {
        float4 w = *(const float4*)(wrow + k);
        acc += w.x * hrow[k] + w.y * hrow[k + 1] + w.z * hrow[k + 2] + w.w * hrow[k + 3];
    }
    hid[tid] = fmaxf(acc, 0.f);
    __syncthreads();

    if (tid < 64) {
        float a2 = fc2b[tid];
        const float* w2 = fc2w + (size_t)tid * 128;
#pragma unroll 4
        for (int k = 0; k < 128; k += 4) {
            float4 w = *(const float4*)(w2 + k);
            a2 += w.x * hid[k] + w.y * hid[k + 1] + w.z * hid[k + 2] + w.w * hid[k + 3];
        }
        float ss = a2 * a2;
#pragma unroll
        for (int off = 32; off > 0; off >>= 1) ss += __shfl_down(ss, off);
        ss = __shfl(ss, 0);
        float scale = 1.f / fmaxf(sqrtf(ss), 1e-12f);
        out[(size_t)row * 64 + tid] = a2 * scale;
    }
}

// ---------------- launcher ----------------
// ws: wih(393216) | whh(786432) | hstate(524288) | xp chunk ((2C+1)*393216)
#define OFF_WIH  ((size_t)0)
#define OFF_WHH  ((size_t)393216)
#define OFF_HST  ((size_t)(393216 + 786432))
#define OFF_XP   ((size_t)(393216 + 786432 + 524288))

extern "C" void kernel_launch(void* const* d_in, const int* in_sizes, int n_in,
                              void* d_out, int out_size, void* d_ws, size_t ws_size,
                              hipStream_t stream) {
    const int*   x      = (const int*)d_in[0];
    const int*   lens   = (const int*)d_in[1];
    const float* embedding = (const float*)d_in[2];
    const float* w_ih_f = (const float*)d_in[3];
    const float* w_hh_f = (const float*)d_in[4];
    const float* b_ih_f = (const float*)d_in[5];
    const float* b_hh_f = (const float*)d_in[6];
    const float* w_ih_b = (const float*)d_in[7];
    const float* w_hh_b = (const float*)d_in[8];
    const float* b_ih_b = (const float*)d_in[9];
    const float* b_hh_b = (const float*)d_in[10];
    const float* fc1_w  = (const float*)d_in[11];
    const float* fc1_b  = (const float*)d_in[12];
    const float* fc2_w  = (const float*)d_in[13];
    const float* fc2_b  = (const float*)d_in[14];
    float* out = (float*)d_out;

    char* ws = (char*)d_ws;
    u16*   wih_bf = (u16*)(ws + OFF_WIH);
    u16*   whh_bf = (u16*)(ws + OFF_WHH);
    float* hstate = (float*)(ws + OFF_HST);
    u16*   xp     = (u16*)(ws + OFF_XP);

    // largest chunk that fits (ws_size constant across calls -> graph-stable)
    int C = 32;
    if      (ws_size >= OFF_XP + (size_t)(2 * 128 + 1) * XP_SLOT_B) C = 128;
    else if (ws_size >= OFF_XP + (size_t)(2 * 64  + 1) * XP_SLOT_B) C = 64;

    f32_to_bf16_kernel<<<192, 256, 0, stream>>>(w_ih_f, wih_bf, 49152);
    f32_to_bf16_kernel<<<192, 256, 0, stream>>>(w_ih_b, wih_bf + 98304, 49152);
    f32_to_bf16_kernel<<<384, 256, 0, stream>>>(w_hh_f, whh_bf, 98304);
    f32_to_bf16_kernel<<<384, 256, 0, stream>>>(w_hh_b, whh_bf + 196608, 98304);

    const int nchunks = T_ / C;
    for (int c = 0; c < nchunks; c++) {
        xp_gemm_kernel<<<8 * C, 512, 0, stream>>>(x, embedding, wih_bf,
                                                  b_ih_f, b_hh_f, b_ih_b, b_hh_b,
                                                  xp, C, c * C);
        gru_chunk_kernel<<<32, 512, 0, stream>>>(xp, whh_bf, b_hh_f, b_hh_b,
                                                 lens, hstate, C, c * C);
    }

    fc_head_kernel<<<256, 128, 0, stream>>>(hstate, fc1_w, fc1_b, fc2_w, fc2_b, out);
}

// Round 7
// 1896.555 us; speedup vs baseline: 1.6299x; 1.6299x over previous
//
#include <hip/hip_runtime.h>
#include <hip/hip_bf16.h>

#define B_ 256
#define T_ 512
#define E_ 128
#define H_ 256

typedef __attribute__((ext_vector_type(8))) short short8;
typedef __attribute__((ext_vector_type(4))) float f32x4;
typedef unsigned short u16;

#define MFMA_BF16(a, b, c) __builtin_amdgcn_mfma_f32_16x16x32_bf16((a), (b), (c), 0, 0, 0)

__device__ __forceinline__ u16 f2bf(float f) {
    union { float f; unsigned int u; } v; v.f = f;
    unsigned int u = v.u;
    unsigned int r = (u + 0x7fffu + ((u >> 16) & 1u)) >> 16;  // RNE
    return (u16)r;
}
__device__ __forceinline__ float bflo(unsigned int u) {
    union { unsigned int u; float f; } v; v.u = u << 16; return v.f;
}
__device__ __forceinline__ float bfhi(unsigned int u) {
    union { unsigned int u; float f; } v; v.u = u & 0xffff0000u; return v.f;
}
__device__ __forceinline__ f32x4 up2(uint2 p) {
    f32x4 r; r[0] = bflo(p.x); r[1] = bfhi(p.x); r[2] = bflo(p.y); r[3] = bfhi(p.y); return r;
}
__device__ __forceinline__ uint2 pk4(float a, float b, float c, float d) {
    uint2 o;
    o.x = (unsigned)f2bf(a) | ((unsigned)f2bf(b) << 16);
    o.y = (unsigned)f2bf(c) | ((unsigned)f2bf(d) << 16);
    return o;
}
__device__ __forceinline__ float sigm(float x) { return 1.f / (1.f + __expf(-x)); }

// ---------------- fp32 -> bf16 weight conversion ----------------
__global__ void f32_to_bf16_kernel(const float* __restrict__ src, u16* __restrict__ dst, int n2) {
    int i = blockIdx.x * blockDim.x + threadIdx.x;
    if (i < n2) {
        float2 v = ((const float2*)src)[i];
        ushort2 o; o.x = f2bf(v.x); o.y = f2bf(v.y);
        ((ushort2*)dst)[i] = o;
    }
}

// ---------------- xp chunk GEMM (R3-proven layout) ----------------
// xp (uint2 per lane): slot = dir*C + lt, then [slot][btile16][gtile48][lane64];
// lane(quad,nl) packs rr=0..3: value = xp(unit gt*16+quad*4+rr, batch btile*16+nl).
// gates r,z (gt<32) carry b_ih+b_hh; n-gate carries b_ih only.
#define XP_SLOT_U2 49152   // 16*48*64 uint2 per t-slot
#define XP_SLOT_B  393216

__launch_bounds__(512, 1)
__global__ void xp_gemm_kernel(const int* __restrict__ x, const float* __restrict__ emb,
                               const u16* __restrict__ wih,
                               const float* __restrict__ bih_f, const float* __restrict__ bhh_f,
                               const float* __restrict__ bih_b, const float* __restrict__ bhh_b,
                               u16* __restrict__ xp, int C, int c0) {
    const int per_dir = C * 4;
    const int dir = (blockIdx.x >= per_dir) ? 1 : 0;
    const int mb  = blockIdx.x - dir * per_dir;
    const int lt  = mb >> 2;
    const int b0  = (mb & 3) << 6;          // 64 batch rows per block
    const int t   = dir ? (T_ - 1 - (c0 + lt)) : (c0 + lt);
    const int tid  = threadIdx.x;
    const int wv   = tid >> 6;
    const int lane = tid & 63;
    const int nl   = lane & 15;
    const int quad = lane >> 4;

    __shared__ u16 A[64][136];

    const u16*   wih_d = wih + (size_t)dir * (768 * 128);
    const float* bih   = dir ? bih_b : bih_f;
    const float* bhh   = dir ? bhh_b : bhh_f;

    short8 wfrag[6][4];
#pragma unroll
    for (int j = 0; j < 6; j++) {
        int gt = wv * 6 + j;
        const u16* p = wih_d + (size_t)(gt * 16 + nl) * 128 + quad * 8;
#pragma unroll
        for (int kt = 0; kt < 4; kt++) wfrag[j][kt] = *(const short8*)(p + kt * 32);
    }

#pragma unroll
    for (int i = 0; i < 4; i++) {
        int idx = tid + i * 512;
        int r = idx >> 5, c = idx & 31;
        int tok = x[(b0 + r) * T_ + t];
        float4 v = *(const float4*)(emb + (size_t)tok * E_ + c * 4);
        *(uint2*)&A[r][c * 4] = pk4(v.x, v.y, v.z, v.w);
    }
    __syncthreads();

    f32x4 acc[6][4];
#pragma unroll
    for (int j = 0; j < 6; j++)
#pragma unroll
        for (int mi = 0; mi < 4; mi++) acc[j][mi] = (f32x4){0, 0, 0, 0};

#pragma unroll
    for (int kt = 0; kt < 4; kt++) {
        short8 a[4];
#pragma unroll
        for (int mi = 0; mi < 4; mi++)
            a[mi] = *(const short8*)&A[mi * 16 + nl][quad * 8 + kt * 32];
#pragma unroll
        for (int j = 0; j < 6; j++)
#pragma unroll
            for (int mi = 0; mi < 4; mi++)
                acc[j][mi] = MFMA_BF16(wfrag[j][kt], a[mi], acc[j][mi]);  // w=A, emb=B
    }

    const int slot = dir * C + lt;
#pragma unroll
    for (int j = 0; j < 6; j++) {
        int gt = wv * 6 + j;
        int gate = gt >> 4;
        const float4 bi = *(const float4*)(bih + gt * 16 + quad * 4);
        const float4 bh = *(const float4*)(bhh + gt * 16 + quad * 4);
        float bb[4];
        bb[0] = bi.x + (gate < 2 ? bh.x : 0.f);
        bb[1] = bi.y + (gate < 2 ? bh.y : 0.f);
        bb[2] = bi.z + (gate < 2 ? bh.z : 0.f);
        bb[3] = bi.w + (gate < 2 ? bh.w : 0.f);
#pragma unroll
        for (int mi = 0; mi < 4; mi++) {
            int btile = ((mb & 3) << 2) + mi;
            f32x4 v = acc[j][mi];
            size_t base = (((size_t)slot * 16 + btile) * 48 + gt) * 64 + lane;
            ((uint2*)xp)[base] = pk4(v[0] + bb[0], v[1] + bb[1], v[2] + bb[2], v[3] + bb[3]);
        }
    }
}

// ---------------- GRU chunk recurrence ----------------
// 32 blocks (dir x 16 btiles), 512 thr = 8 waves.
// LDS = 24 KB hfr (padded) + 64 KB wn = 88 KB -> HARD 1 block/CU, 2 waves/SIMD.
// __launch_bounds__(512,2) -> RA budget 256 regs/wave.
// Wave wv owns units [wv*32, wv*32+32); lane(quad,nl): batch b_base+nl,
// units wv*32+16*hh+quad*4+rr.
// Weight residency: 5 sets (r,h0)(r,h1)(z,h0)(z,h1)(n,h0) = 160 VGPR, made
// UN-REMATERIALIZABLE by a one-time opaque asm redefinition after the load
// (the value's def is no longer a load, so the scheduler cannot sink/remat
// it into the loop — the R3..R6 failure mode). 6th set (n,h1) in LDS.
__launch_bounds__(512, 2)
__global__ void gru_chunk_kernel(const u16* __restrict__ xp, const u16* __restrict__ whh,
                                 const float* __restrict__ bhh_f, const float* __restrict__ bhh_b,
                                 const int* __restrict__ lengths,
                                 float* __restrict__ hstate,   // [dir][256][256] f32
                                 int C, int c0) {
    const int dir    = blockIdx.x >> 4;
    const int btile  = blockIdx.x & 15;
    const int b_base = btile << 4;
    const int wv     = threadIdx.x >> 6;
    const int lane   = threadIdx.x & 63;
    const int nl     = lane & 15;
    const int quad   = lane >> 4;

    // hfr rows padded 4096->6144 u16: pure LDS pad to push block to 88 KB
    // (>80 KB) so occupancy is pinned at 1 block/CU = 2 waves/SIMD.
    __shared__ u16 hfr[2][6144];     // h mirrors, fragment-linear (first 4096 used)
    __shared__ u16 wn[32768];        // 64KB: (n,h1) weight set, fragment-linear

    const u16*   whh_d = whh + (size_t)dir * (768 * 256);
    const float* bhh   = dir ? bhh_b : bhh_f;

    // stage wn: entry (wv_e,kt_e,ln_e) <- whh row 512+wv_e*32+16+(ln_e&15),
    // cols (ln_e>>4)*8 + kt_e*32
    for (int e = threadIdx.x; e < 4096; e += 512) {
        int wv_e = e >> 9, kt_e = (e >> 6) & 7, ln_e = e & 63;
        const u16* src = whh_d + (size_t)(512 + wv_e * 32 + 16 + (ln_e & 15)) * 256
                       + (ln_e >> 4) * 8 + kt_e * 32;
        *(short8*)&wn[e * 8] = *(const short8*)src;
    }

    // register w_hh sets: (r,h0)(r,h1)(z,h0)(z,h1)(n,h0)
    short8 w[5][8];
    {
        const int row[5] = {wv * 32 + nl, wv * 32 + 16 + nl,
                            256 + wv * 32 + nl, 256 + wv * 32 + 16 + nl,
                            512 + wv * 32 + nl};
#pragma unroll
        for (int gh = 0; gh < 5; gh++) {
            const u16* p = whh_d + (size_t)row[gh] * 256 + quad * 8;
#pragma unroll
            for (int kt = 0; kt < 8; kt++) w[gh][kt] = *(const short8*)(p + kt * 32);
        }
    }
    // ONE-TIME opaque redefinition (zero instructions): blocks load-remat /
    // load-sinking of the weight sets into the step loop. NOT inside the loop.
#pragma unroll
    for (int gh = 0; gh < 5; gh++)
        asm volatile("" : "+v"(w[gh][0]), "+v"(w[gh][1]), "+v"(w[gh][2]), "+v"(w[gh][3]),
                          "+v"(w[gh][4]), "+v"(w[gh][5]), "+v"(w[gh][6]), "+v"(w[gh][7]));

    const float4 bnh0 = *(const float4*)(bhh + 512 + wv * 32 + quad * 4);
    const float4 bnh1 = *(const float4*)(bhh + 512 + wv * 32 + 16 + quad * 4);
    const int len = lengths[b_base + nl];

    // h master copy (fp32) + initial mirror write
    float hreg[2][4];
    const int o0 = quad * 4, o1 = 16 + quad * 4;
    const int widx0 = (wv * 64 + (o0 >> 3) * 16 + nl) * 8 + (o0 & 7);
    const int widx1 = (wv * 64 + (o1 >> 3) * 16 + nl) * 8 + (o1 & 7);
    if (c0 == 0) {
#pragma unroll
        for (int hh = 0; hh < 2; hh++)
#pragma unroll
            for (int rr = 0; rr < 4; rr++) hreg[hh][rr] = 0.f;
    } else {
        const float* hs = hstate + ((size_t)(dir * 256 + b_base + nl)) * 256 + wv * 32;
        float4 h0 = *(const float4*)(hs + o0);
        float4 h1 = *(const float4*)(hs + o1);
        hreg[0][0] = h0.x; hreg[0][1] = h0.y; hreg[0][2] = h0.z; hreg[0][3] = h0.w;
        hreg[1][0] = h1.x; hreg[1][1] = h1.y; hreg[1][2] = h1.z; hreg[1][3] = h1.w;
    }
    *(uint2*)&hfr[0][widx0] = pk4(hreg[0][0], hreg[0][1], hreg[0][2], hreg[0][3]);
    *(uint2*)&hfr[0][widx1] = pk4(hreg[1][0], hreg[1][1], hreg[1][2], hreg[1][3]);

    // xp pointers: gate g tile for this wave = g*16 + wv*2 (+hh)
    const uint2* pg0;
    const uint2* pg1;
    const uint2* pg2;
    {
        size_t base = (((size_t)(dir * C) * 16 + btile) * 48) * 64 + lane;
        pg0 = (const uint2*)xp + base + (0 * 16 + wv * 2) * 64;
        pg1 = (const uint2*)xp + base + (1 * 16 + wv * 2) * 64;
        pg2 = (const uint2*)xp + base + (2 * 16 + wv * 2) * 64;
    }
    uint2 pf0[2], pf1[2], pf2[2];
    pf0[0] = pg0[0]; pf0[1] = pg0[64];
    pf1[0] = pg1[0]; pf1[1] = pg1[64];
    pf2[0] = pg2[0]; pf2[1] = pg2[64];

    __syncthreads();

    for (int ls = 0; ls < C; ls++) {
        const int s = c0 + ls;
        const int t = dir ? (T_ - 1 - s) : s;
        const int cur = ls & 1, nxt = cur ^ 1;

        // consume prefetched xp
        f32x4 accr[2], accz[2], accn[2], xpn[2];
        accr[0] = up2(pf0[0]); accr[1] = up2(pf0[1]);
        accz[0] = up2(pf1[0]); accz[1] = up2(pf1[1]);
        xpn[0]  = up2(pf2[0]); xpn[1]  = up2(pf2[1]);
        accn[0] = (f32x4){bnh0.x, bnh0.y, bnh0.z, bnh0.w};
        accn[1] = (f32x4){bnh1.x, bnh1.y, bnh1.z, bnh1.w};

        // prefetch next step (last iter reads the pad/next-dir slot — valid, unused)
        pg0 += XP_SLOT_U2; pg1 += XP_SLOT_U2; pg2 += XP_SLOT_U2;
        pf0[0] = pg0[0]; pf0[1] = pg0[64];
        pf1[0] = pg1[0]; pf1[1] = pg1[64];
        pf2[0] = pg2[0]; pf2[1] = pg2[64];

#pragma unroll
        for (int kt = 0; kt < 8; kt++) {
            short8 hv = *(const short8*)&hfr[cur][(kt * 64 + lane) * 8];
            accr[0] = MFMA_BF16(w[0][kt], hv, accr[0]);
            accr[1] = MFMA_BF16(w[1][kt], hv, accr[1]);
            accz[0] = MFMA_BF16(w[2][kt], hv, accz[0]);
            accz[1] = MFMA_BF16(w[3][kt], hv, accz[1]);
            accn[0] = MFMA_BF16(w[4][kt], hv, accn[0]);
            short8 bn = *(const short8*)&wn[((wv * 8 + kt) * 64 + lane) * 8];
            accn[1] = MFMA_BF16(bn, hv, accn[1]);
        }

        const bool upd = (t < len);
#pragma unroll
        for (int hh = 0; hh < 2; hh++) {
#pragma unroll
            for (int rr = 0; rr < 4; rr++) {
                float r = sigm(accr[hh][rr]);
                float z = sigm(accz[hh][rr]);
                float npre = xpn[hh][rr] + r * accn[hh][rr];
                float nn = 1.f - 2.f / (1.f + __expf(2.f * npre));
                float hn = nn + z * (hreg[hh][rr] - nn);
                if (upd) hreg[hh][rr] = hn;
            }
        }
        *(uint2*)&hfr[nxt][widx0] = pk4(hreg[0][0], hreg[0][1], hreg[0][2], hreg[0][3]);
        *(uint2*)&hfr[nxt][widx1] = pk4(hreg[1][0], hreg[1][1], hreg[1][2], hreg[1][3]);
        __syncthreads();
    }

    // carry h out (coalesced float4)
    float* hs = hstate + ((size_t)(dir * 256 + b_base + nl)) * 256 + wv * 32;
    *(float4*)(hs + o0) = (float4){hreg[0][0], hreg[0][1], hreg[0][2], hreg[0][3]};
    *(float4*)(hs + o1) = (float4){hreg[1][0], hreg[1][1], hreg[1][2], hreg[1][3]};
}

// ---------------- FC head + row L2-normalize ----------------
__global__ void fc_head_kernel(const float* __restrict__ hstate,
                               const float* __restrict__ fc1w, const float* __restrict__ fc1b,
                               const float* __restrict__ fc2w, const float* __restrict__ fc2b,
                               float* __restrict__ out) {
    int row = blockIdx.x;
    int tid = threadIdx.x;  // 128
    __shared__ float hrow[512];
    __shared__ float hid[128];

    {
        int dir = tid >> 6, u = (tid & 63) * 4;
        float4 hv = *(const float4*)(hstate + ((size_t)(dir * 256 + row)) * 256 + u);
        *(float4*)(hrow + tid * 4) = hv;
    }
    __syncthreads();

    float acc = fc1b[tid];
    const float* wrow = fc1w + (size_t)tid * 512;
#pragma unroll 4
    for (int k = 0; k < 512; k += 4) {
        float4 w = *(const float4*)(wrow + k);
        acc += w.x * hrow[k] + w.y * hrow[k + 1] + w.z * hrow[k + 2] + w.w * hrow[k + 3];
    }
    hid[tid] = fmaxf(acc, 0.f);
    __syncthreads();

    if (tid < 64) {
        float a2 = fc2b[tid];
        const float* w2 = fc2w + (size_t)tid * 128;
#pragma unroll 4
        for (int k = 0; k < 128; k += 4) {
            float4 w = *(const float4*)(w2 + k);
            a2 += w.x * hid[k] + w.y * hid[k + 1] + w.z * hid[k + 2] + w.w * hid[k + 3];
        }
        float ss = a2 * a2;
#pragma unroll
        for (int off = 32; off > 0; off >>= 1) ss += __shfl_down(ss, off);
        ss = __shfl(ss, 0);
        float scale = 1.f / fmaxf(sqrtf(ss), 1e-12f);
        out[(size_t)row * 64 + tid] = a2 * scale;
    }
}

// ---------------- launcher ----------------
// ws: wih(393216) | whh(786432) | hstate(524288) | xp chunk ((2C+1)*393216)
#define OFF_WIH  ((size_t)0)
#define OFF_WHH  ((size_t)393216)
#define OFF_HST  ((size_t)(393216 + 786432))
#define OFF_XP   ((size_t)(393216 + 786432 + 524288))

extern "C" void kernel_launch(void* const* d_in, const int* in_sizes, int n_in,
                              void* d_out, int out_size, void* d_ws, size_t ws_size,
                              hipStream_t stream) {
    const int*   x      = (const int*)d_in[0];
    const int*   lens   = (const int*)d_in[1];
    const float* embedding = (const float*)d_in[2];
    const float* w_ih_f = (const float*)d_in[3];
    const float* w_hh_f = (const float*)d_in[4];
    const float* b_ih_f = (const float*)d_in[5];
    const float* b_hh_f = (const float*)d_in[6];
    const float* w_ih_b = (const float*)d_in[7];
    const float* w_hh_b = (const float*)d_in[8];
    const float* b_ih_b = (const float*)d_in[9];
    const float* b_hh_b = (const float*)d_in[10];
    const float* fc1_w  = (const float*)d_in[11];
    const float* fc1_b  = (const float*)d_in[12];
    const float* fc2_w  = (const float*)d_in[13];
    const float* fc2_b  = (const float*)d_in[14];
    float* out = (float*)d_out;

    char* ws = (char*)d_ws;
    u16*   wih_bf = (u16*)(ws + OFF_WIH);
    u16*   whh_bf = (u16*)(ws + OFF_WHH);
    float* hstate = (float*)(ws + OFF_HST);
    u16*   xp     = (u16*)(ws + OFF_XP);

    // largest chunk that fits (ws_size constant across calls -> graph-stable)
    int C = 32;
    if      (ws_size >= OFF_XP + (size_t)(2 * 128 + 1) * XP_SLOT_B) C = 128;
    else if (ws_size >= OFF_XP + (size_t)(2 * 64  + 1) * XP_SLOT_B) C = 64;

    f32_to_bf16_kernel<<<192, 256, 0, stream>>>(w_ih_f, wih_bf, 49152);
    f32_to_bf16_kernel<<<192, 256, 0, stream>>>(w_ih_b, wih_bf + 98304, 49152);
    f32_to_bf16_kernel<<<384, 256, 0, stream>>>(w_hh_f, whh_bf, 98304);
    f32_to_bf16_kernel<<<384, 256, 0, stream>>>(w_hh_b, whh_bf + 196608, 98304);

    const int nchunks = T_ / C;
    for (int c = 0; c < nchunks; c++) {
        xp_gemm_kernel<<<8 * C, 512, 0, stream>>>(x, embedding, wih_bf,
                                                  b_ih_f, b_hh_f, b_ih_b, b_hh_b,
                                                  xp, C, c * C);
        gru_chunk_kernel<<<32, 512, 0, stream>>>(xp, whh_bf, b_hh_f, b_hh_b,
                                                 lens, hstate, C, c * C);
    }

    fc_head_kernel<<<256, 128, 0, stream>>>(hstate, fc1_w, fc1_b, fc2_w, fc2_b, out);
}